// Round 2
// baseline (10799.773 us; speedup 1.0000x reference)
//
#include <hip/hip_runtime.h>
#include <math.h>

#define B_ 8
#define T_ 1024
#define IN_DIM 80
#define DM 256
#define NH 4
#define DKH 64
#define FFD 2048
#define NL 6
#define PE_ROWS (2*T_-1)   /* 2047 */
#define ROWS (B_*T_)       /* 8192 */

// ---------------- embed + BasicNorm ----------------
__global__ void embed_norm_kernel(const float* __restrict__ x,
                                  const float* __restrict__ W,
                                  const float* __restrict__ b,
                                  float* __restrict__ out) {
  const int row = blockIdx.x;           // 0..ROWS-1
  const int t = threadIdx.x;            // 0..255 (= output channel)
  __shared__ float xin[IN_DIM];
  __shared__ float red[4];
  if (t < IN_DIM) xin[t] = x[(long)row*IN_DIM + t];
  __syncthreads();
  float v = b[t];
  const float* wr = W + (long)t*IN_DIM;
  #pragma unroll 8
  for (int k = 0; k < IN_DIM; ++k) v = fmaf(xin[k], wr[k], v);
  float sq = v*v;
  for (int o = 32; o > 0; o >>= 1) sq += __shfl_down(sq, o);
  if ((t & 63) == 0) red[t >> 6] = sq;
  __syncthreads();
  const float tot = red[0] + red[1] + red[2] + red[3];
  const float sc = 1.0f / sqrtf(tot * (1.0f/DM) + 0.25f);
  out[(long)row*DM + t] = v * sc;
}

// ---------------- BasicNorm (row over 256 ch) ----------------
__global__ void norm_kernel(const float* __restrict__ in, float* __restrict__ out) {
  const int row = blockIdx.x;
  const int t = threadIdx.x;            // 256
  __shared__ float red[4];
  const float v = in[(long)row*DM + t];
  float sq = v*v;
  for (int o = 32; o > 0; o >>= 1) sq += __shfl_down(sq, o);
  if ((t & 63) == 0) red[t >> 6] = sq;
  __syncthreads();
  const float tot = red[0] + red[1] + red[2] + red[3];
  out[(long)row*DM + t] = v * (1.0f / sqrtf(tot * (1.0f/DM) + 0.25f));
}

// ---------------- relative positional encoding table ----------------
__global__ void pe_kernel(float* __restrict__ pe) {
  const int r = blockIdx.x;             // 0..2046
  const int c = threadIdx.x;            // 0..255
  const int m = c >> 1;
  const float div = expf((float)(2*m) * -0.0359778921f);
  const float ang = (float)(T_ - 1 - r) * div;
  pe[(long)r*DM + c] = (c & 1) ? cosf(ang) : sinf(ang);
}

// ---------------- tiled GEMM: C = A @ W^T (+bias)(+act)(+res) ----------------
// A: (M,K) row-major, W: (N,K) row-major. Tile: (64*MH) x (64*NHC), BK=16,
// 256 threads, micro-tile (4*MH)x(4*NHC) per thread via two 64-row halves.
// ACT: 0=none, 1=double_swish.
template<int MH, int NHC, int ACT, bool BIAS, bool RES>
__global__ __launch_bounds__(256) void gemm_nt(
    const float* __restrict__ A, const float* __restrict__ W,
    const float* __restrict__ bias, const float* __restrict__ res,
    float* __restrict__ C, int M, int N, int K,
    long sA, long sW, long sB, long sC) {
  constexpr int TM = 64*MH, TN = 64*NHC;
  const int z = blockIdx.z;
  A += (long)z * sA; W += (long)z * sW; C += (long)z * sC;
  if (BIAS) bias += (long)z * sB;
  if (RES)  res  += (long)z * sC;
  __shared__ __align__(16) float As[16][TM+4];   // [k][m] (A transposed in LDS)
  __shared__ __align__(16) float Bs[16][TN+4];   // [k][n]
  const int t = threadIdx.x;
  const int tx = t & 15, ty = t >> 4;
  const int m0 = blockIdx.x * TM, n0 = blockIdx.y * TN;
  float acc[4*MH][4*NHC] = {};
  for (int k0 = 0; k0 < K; k0 += 16) {
    #pragma unroll
    for (int i = 0; i < MH; ++i) {
      const int e = t + i*256;            // 0 .. TM*4-1
      const int row = e >> 2, kq = (e & 3) * 4;
      const int gm = m0 + row;
      float4 v = make_float4(0.f, 0.f, 0.f, 0.f);
      if (gm < M) v = *(const float4*)(A + (long)gm*K + k0 + kq);
      As[kq+0][row] = v.x; As[kq+1][row] = v.y;
      As[kq+2][row] = v.z; As[kq+3][row] = v.w;
    }
    #pragma unroll
    for (int i = 0; i < NHC; ++i) {
      const int e = t + i*256;
      const int row = e >> 2, kq = (e & 3) * 4;
      const float4 v = *(const float4*)(W + (long)(n0+row)*K + k0 + kq);
      Bs[kq+0][row] = v.x; Bs[kq+1][row] = v.y;
      Bs[kq+2][row] = v.z; Bs[kq+3][row] = v.w;
    }
    __syncthreads();
    #pragma unroll
    for (int kk = 0; kk < 16; ++kk) {
      float a[4*MH], bb[4*NHC];
      #pragma unroll
      for (int h = 0; h < MH; ++h) {
        const float4 v = *(const float4*)&As[kk][h*64 + ty*4];
        a[h*4+0]=v.x; a[h*4+1]=v.y; a[h*4+2]=v.z; a[h*4+3]=v.w;
      }
      #pragma unroll
      for (int h = 0; h < NHC; ++h) {
        const float4 v = *(const float4*)&Bs[kk][h*64 + tx*4];
        bb[h*4+0]=v.x; bb[h*4+1]=v.y; bb[h*4+2]=v.z; bb[h*4+3]=v.w;
      }
      #pragma unroll
      for (int q = 0; q < 4*MH; ++q)
        #pragma unroll
        for (int r = 0; r < 4*NHC; ++r)
          acc[q][r] = fmaf(a[q], bb[r], acc[q][r]);
    }
    __syncthreads();
  }
  #pragma unroll
  for (int q = 0; q < 4*MH; ++q) {
    const int gm = m0 + (q>>2)*64 + ty*4 + (q&3);
    if (gm >= M) continue;
    #pragma unroll
    for (int h = 0; h < NHC; ++h) {
      const int gn = n0 + h*64 + tx*4;
      float4 v = make_float4(acc[q][h*4+0], acc[q][h*4+1],
                             acc[q][h*4+2], acc[q][h*4+3]);
      if (BIAS) {
        const float4 b4 = *(const float4*)(bias + gn);
        v.x += b4.x; v.y += b4.y; v.z += b4.z; v.w += b4.w;
      }
      if (ACT == 1) {                       // x * sigmoid(x-1)
        v.x = v.x / (1.0f + expf(1.0f - v.x));
        v.y = v.y / (1.0f + expf(1.0f - v.y));
        v.z = v.z / (1.0f + expf(1.0f - v.z));
        v.w = v.w / (1.0f + expf(1.0f - v.w));
      }
      if (RES) {
        const float4 r4 = *(const float4*)(res + (long)gm*N + gn);
        v.x += r4.x; v.y += r4.y; v.z += r4.z; v.w += r4.w;
      }
      *(float4*)(C + (long)gm*N + gn) = v;
    }
  }
}

// ---------------- fused attention: one block per (b, h, i) row ----------------
__global__ __launch_bounds__(256) void attn_kernel(
    const float* __restrict__ qkv,   // (ROWS, 768) q|k|v
    const float* __restrict__ p,     // (2T-1, 256) per-layer
    const float* __restrict__ bu,    // (4*64)
    const float* __restrict__ bv,    // (4*64)
    const int*   __restrict__ lens,  // (B)
    float* __restrict__ att) {       // (ROWS, 256)
  const int i = blockIdx.x;
  const int h = blockIdx.y;
  const int b = blockIdx.z;
  const int t = threadIdx.x;         // 256
  __shared__ __align__(16) float qu[DKH];
  __shared__ __align__(16) float qv[DKH];
  __shared__ float s[T_];
  __shared__ float part[4][DKH];
  __shared__ float red[4];
  const int len = lens[b];
  if (t < DKH) {
    const float q = qkv[((long)(b*T_ + i))*(3*DM) + h*DKH + t];
    qu[t] = q + bu[h*DKH + t];
    qv[t] = q + bv[h*DKH + t];
  }
  __syncthreads();
  float lmax = -1e30f;
  #pragma unroll
  for (int jj = 0; jj < 4; ++jj) {
    const int j = t + jj*256;
    float sc = -1e30f;                 // masked value (unscaled), as reference
    if (j <= i && j < len) {
      const float4* kp = (const float4*)(qkv + ((long)(b*T_ + j))*(3*DM) + DM + h*DKH);
      const float4* pp = (const float4*)(p + (long)(T_ - 1 - i + j)*DM + h*DKH);
      const float4* up = (const float4*)qu;
      const float4* vp = (const float4*)qv;
      float acc = 0.0f, acb = 0.0f;
      #pragma unroll
      for (int d4 = 0; d4 < DKH/4; ++d4) {
        const float4 kk = kp[d4], pv = pp[d4], uu = up[d4], vv = vp[d4];
        acc = fmaf(uu.x, kk.x, acc); acc = fmaf(uu.y, kk.y, acc);
        acc = fmaf(uu.z, kk.z, acc); acc = fmaf(uu.w, kk.w, acc);
        acb = fmaf(vv.x, pv.x, acb); acb = fmaf(vv.y, pv.y, acb);
        acb = fmaf(vv.z, pv.z, acb); acb = fmaf(vv.w, pv.w, acb);
      }
      sc = (acc + acb) * 0.125f;       // DK^-0.5
    }
    s[j] = sc;
    lmax = fmaxf(lmax, sc);
  }
  for (int o = 32; o > 0; o >>= 1) lmax = fmaxf(lmax, __shfl_down(lmax, o));
  if ((t & 63) == 0) red[t >> 6] = lmax;
  __syncthreads();
  const float m = fmaxf(fmaxf(red[0], red[1]), fmaxf(red[2], red[3]));
  float lsum = 0.0f;
  #pragma unroll
  for (int jj = 0; jj < 4; ++jj) {
    const int j = t + jj*256;
    const float e = expf(s[j] - m);
    s[j] = e;
    lsum += e;
  }
  for (int o = 32; o > 0; o >>= 1) lsum += __shfl_down(lsum, o);
  __syncthreads();
  if ((t & 63) == 0) red[t >> 6] = lsum;
  __syncthreads();
  const float inv = 1.0f / (red[0] + red[1] + red[2] + red[3]);
  const int d = t & 63, g = t >> 6;
  const int jmax = min(i, len - 1);    // s[j] == 0 beyond this
  float acc = 0.0f;
  for (int j = g; j <= jmax; j += 4) {
    acc = fmaf(s[j], qkv[((long)(b*T_ + j))*(3*DM) + 2*DM + h*DKH + d], acc);
  }
  part[g][d] = acc;
  __syncthreads();
  if (g == 0) {
    const float o = (part[0][d] + part[1][d] + part[2][d] + part[3][d]) * inv;
    att[((long)(b*T_ + i))*DM + h*DKH + d] = o;
  }
}

// ---------------- x_lens tail of the tuple output ----------------
__global__ void tail_kernel(const int* __restrict__ lens, float* __restrict__ out) {
  const int i = threadIdx.x;
  if (i < B_) out[(long)ROWS*DM + i] = (float)lens[i];
}

extern "C" void kernel_launch(void* const* d_in, const int* in_sizes, int n_in,
                              void* d_out, int out_size, void* d_ws, size_t ws_size,
                              hipStream_t stream) {
  const float* x    = (const float*)d_in[0];
  const int*   lens = (const int*)  d_in[1];
  const float* embW = (const float*)d_in[2];
  const float* embB = (const float*)d_in[3];
  const float* ipW  = (const float*)d_in[4];
  const float* ipB  = (const float*)d_in[5];
  const float* posW = (const float*)d_in[6];
  const float* bu   = (const float*)d_in[7];
  const float* bv   = (const float*)d_in[8];
  const float* oW   = (const float*)d_in[9];
  const float* oB   = (const float*)d_in[10];
  const float* f1W  = (const float*)d_in[11];
  const float* f1B  = (const float*)d_in[12];
  const float* f2W  = (const float*)d_in[13];
  const float* f2B  = (const float*)d_in[14];
  float* out = (float*)d_out;

  float* ws   = (float*)d_ws;
  float* xbuf = ws;                              // ROWS*DM
  float* pe   = xbuf + (long)ROWS*DM;            // PE_ROWS*DM
  float* pall = pe   + (long)PE_ROWS*DM;         // NL*PE_ROWS*DM
  float* qkv  = pall + (long)NL*PE_ROWS*DM;      // ROWS*768
  float* att  = qkv  + (long)ROWS*3*DM;          // ROWS*DM
  float* ff   = att  + (long)ROWS*DM;            // ROWS*FFD

  embed_norm_kernel<<<ROWS, 256, 0, stream>>>(x, embW, embB, xbuf);
  pe_kernel<<<PE_ROWS, 256, 0, stream>>>(pe);
  // p_all[l] = pe @ pos_W[l]^T  (batched over layers; M=2047 needs guards)
  gemm_nt<2,1,0,false,false><<<dim3((PE_ROWS+127)/128, DM/64, NL), 256, 0, stream>>>(
      pe, posW, nullptr, nullptr, pall, PE_ROWS, DM, DM,
      0L, (long)DM*DM, 0L, (long)PE_ROWS*DM);

  for (int l = 0; l < NL; ++l) {
    // qkv = x @ in_proj^T + b   (M=8192, N=768, K=256)
    gemm_nt<2,2,0,true,false><<<dim3(ROWS/128, (3*DM)/128, 1), 256, 0, stream>>>(
        xbuf, ipW + (long)l*3*DM*DM, ipB + (long)l*3*DM, nullptr, qkv,
        ROWS, 3*DM, DM, 0,0,0,0);
    attn_kernel<<<dim3(T_, NH, B_), 256, 0, stream>>>(
        qkv, pall + (long)l*PE_ROWS*DM, bu + (long)l*DM, bv + (long)l*DM, lens, att);
    // x += att @ oW^T + oB   (N=256 -> 128x64 tiles, 256 blocks)
    gemm_nt<2,1,0,true,true><<<dim3(ROWS/128, DM/64, 1), 256, 0, stream>>>(
        att, oW + (long)l*DM*DM, oB + (long)l*DM, xbuf, xbuf, ROWS, DM, DM, 0,0,0,0);
    // h = dswish(x @ f1^T + b1)  (N=2048)
    gemm_nt<2,2,1,true,false><<<dim3(ROWS/128, FFD/128, 1), 256, 0, stream>>>(
        xbuf, f1W + (long)l*FFD*DM, f1B + (long)l*FFD, nullptr, ff, ROWS, FFD, DM, 0,0,0,0);
    // x += h @ f2^T + b2  (K=2048, N=256)
    gemm_nt<2,1,0,true,true><<<dim3(ROWS/128, DM/64, 1), 256, 0, stream>>>(
        ff, f2W + (long)l*DM*FFD, f2B + (long)l*DM, xbuf, xbuf, ROWS, DM, FFD, 0,0,0,0);
    norm_kernel<<<ROWS, 256, 0, stream>>>(xbuf, (l == NL-1) ? out : xbuf);
  }
  tail_kernel<<<1, 64, 0, stream>>>(lens, out);
}

// Round 3
// 4794.872 us; speedup vs baseline: 2.2524x; 2.2524x over previous
//
#include <hip/hip_runtime.h>
#include <math.h>

#define B_ 8
#define T_ 1024
#define IN_DIM 80
#define DM 256
#define NH 4
#define DKH 64
#define FFD 2048
#define NL 6
#define PE_ROWS (2*T_-1)   /* 2047 */
#define ROWS (B_*T_)       /* 8192 */

// ---------------- embed + BasicNorm ----------------
__global__ void embed_norm_kernel(const float* __restrict__ x,
                                  const float* __restrict__ W,
                                  const float* __restrict__ b,
                                  float* __restrict__ out) {
  const int row = blockIdx.x;           // 0..ROWS-1
  const int t = threadIdx.x;            // 0..255 (= output channel)
  __shared__ float xin[IN_DIM];
  __shared__ float red[4];
  if (t < IN_DIM) xin[t] = x[(long)row*IN_DIM + t];
  __syncthreads();
  float v = b[t];
  const float* wr = W + (long)t*IN_DIM;
  #pragma unroll 8
  for (int k = 0; k < IN_DIM; ++k) v = fmaf(xin[k], wr[k], v);
  float sq = v*v;
  for (int o = 32; o > 0; o >>= 1) sq += __shfl_down(sq, o);
  if ((t & 63) == 0) red[t >> 6] = sq;
  __syncthreads();
  const float tot = red[0] + red[1] + red[2] + red[3];
  const float sc = 1.0f / sqrtf(tot * (1.0f/DM) + 0.25f);
  out[(long)row*DM + t] = v * sc;
}

// ---------------- BasicNorm (row over 256 ch) ----------------
__global__ void norm_kernel(const float* __restrict__ in, float* __restrict__ out) {
  const int row = blockIdx.x;
  const int t = threadIdx.x;            // 256
  __shared__ float red[4];
  const float v = in[(long)row*DM + t];
  float sq = v*v;
  for (int o = 32; o > 0; o >>= 1) sq += __shfl_down(sq, o);
  if ((t & 63) == 0) red[t >> 6] = sq;
  __syncthreads();
  const float tot = red[0] + red[1] + red[2] + red[3];
  out[(long)row*DM + t] = v * (1.0f / sqrtf(tot * (1.0f/DM) + 0.25f));
}

// ---------------- relative positional encoding table ----------------
__global__ void pe_kernel(float* __restrict__ pe) {
  const int r = blockIdx.x;             // 0..2046
  const int c = threadIdx.x;            // 0..255
  const int m = c >> 1;
  const float div = expf((float)(2*m) * -0.0359778921f);
  const float ang = (float)(T_ - 1 - r) * div;
  pe[(long)r*DM + c] = (c & 1) ? cosf(ang) : sinf(ang);
}

// ---------------- tiled GEMM: C = A @ W^T (+bias)(+act)(+res) ----------------
template<int MH, int NHC, int ACT, bool BIAS, bool RES>
__global__ __launch_bounds__(256) void gemm_nt(
    const float* __restrict__ A, const float* __restrict__ W,
    const float* __restrict__ bias, const float* __restrict__ res,
    float* __restrict__ C, int M, int N, int K,
    long sA, long sW, long sB, long sC) {
  constexpr int TM = 64*MH, TN = 64*NHC;
  const int z = blockIdx.z;
  A += (long)z * sA; W += (long)z * sW; C += (long)z * sC;
  if (BIAS) bias += (long)z * sB;
  if (RES)  res  += (long)z * sC;
  __shared__ __align__(16) float As[16][TM+4];   // [k][m] (A transposed in LDS)
  __shared__ __align__(16) float Bs[16][TN+4];   // [k][n]
  const int t = threadIdx.x;
  const int tx = t & 15, ty = t >> 4;
  const int m0 = blockIdx.x * TM, n0 = blockIdx.y * TN;
  float acc[4*MH][4*NHC] = {};
  for (int k0 = 0; k0 < K; k0 += 16) {
    #pragma unroll
    for (int i = 0; i < MH; ++i) {
      const int e = t + i*256;            // 0 .. TM*4-1
      const int row = e >> 2, kq = (e & 3) * 4;
      const int gm = m0 + row;
      float4 v = make_float4(0.f, 0.f, 0.f, 0.f);
      if (gm < M) v = *(const float4*)(A + (long)gm*K + k0 + kq);
      As[kq+0][row] = v.x; As[kq+1][row] = v.y;
      As[kq+2][row] = v.z; As[kq+3][row] = v.w;
    }
    #pragma unroll
    for (int i = 0; i < NHC; ++i) {
      const int e = t + i*256;
      const int row = e >> 2, kq = (e & 3) * 4;
      const float4 v = *(const float4*)(W + (long)(n0+row)*K + k0 + kq);
      Bs[kq+0][row] = v.x; Bs[kq+1][row] = v.y;
      Bs[kq+2][row] = v.z; Bs[kq+3][row] = v.w;
    }
    __syncthreads();
    #pragma unroll
    for (int kk = 0; kk < 16; ++kk) {
      float a[4*MH], bb[4*NHC];
      #pragma unroll
      for (int h = 0; h < MH; ++h) {
        const float4 v = *(const float4*)&As[kk][h*64 + ty*4];
        a[h*4+0]=v.x; a[h*4+1]=v.y; a[h*4+2]=v.z; a[h*4+3]=v.w;
      }
      #pragma unroll
      for (int h = 0; h < NHC; ++h) {
        const float4 v = *(const float4*)&Bs[kk][h*64 + tx*4];
        bb[h*4+0]=v.x; bb[h*4+1]=v.y; bb[h*4+2]=v.z; bb[h*4+3]=v.w;
      }
      #pragma unroll
      for (int q = 0; q < 4*MH; ++q)
        #pragma unroll
        for (int r = 0; r < 4*NHC; ++r)
          acc[q][r] = fmaf(a[q], bb[r], acc[q][r]);
    }
    __syncthreads();
  }
  #pragma unroll
  for (int q = 0; q < 4*MH; ++q) {
    const int gm = m0 + (q>>2)*64 + ty*4 + (q&3);
    if (gm >= M) continue;
    #pragma unroll
    for (int h = 0; h < NHC; ++h) {
      const int gn = n0 + h*64 + tx*4;
      float4 v = make_float4(acc[q][h*4+0], acc[q][h*4+1],
                             acc[q][h*4+2], acc[q][h*4+3]);
      if (BIAS) {
        const float4 b4 = *(const float4*)(bias + gn);
        v.x += b4.x; v.y += b4.y; v.z += b4.z; v.w += b4.w;
      }
      if (ACT == 1) {                       // x * sigmoid(x-1)
        v.x = v.x / (1.0f + expf(1.0f - v.x));
        v.y = v.y / (1.0f + expf(1.0f - v.y));
        v.z = v.z / (1.0f + expf(1.0f - v.z));
        v.w = v.w / (1.0f + expf(1.0f - v.w));
      }
      if (RES) {
        const float4 r4 = *(const float4*)(res + (long)gm*N + gn);
        v.x += r4.x; v.y += r4.y; v.z += r4.z; v.w += r4.w;
      }
      *(float4*)(C + (long)gm*N + gn) = v;
    }
  }
}

// ---------------- flash attention: one block per (b, h, 64-row i-tile) ----------------
// S[i][j] = ((q_i+bu)·k_j + (q_i+bv)·p[T-1-i+j]) * DK^-0.5, causal+len mask.
// bd term: thread (tx,ty) needs P-window cols c = 63+(dj-di) = c0m3+ (r-q+3),
// a 4-aligned 8-col slab per thread -> computed fully in registers (bd[4][8]).
__global__ __launch_bounds__(256) void attn_flash(
    const float* __restrict__ qkv,   // (ROWS, 768) q|k|v
    const float* __restrict__ p,     // (2T-1, 256) per-layer
    const float* __restrict__ bu, const float* __restrict__ bv,
    const int* __restrict__ lens,
    float* __restrict__ att) {       // (ROWS, 256)
  const int itile = (int)gridDim.x - 1 - (int)blockIdx.x;  // heavy tiles first
  const int h = blockIdx.y, b = blockIdx.z;
  const int t = threadIdx.x;         // 256
  const int tx = t & 15, ty = t >> 4;
  const int i0 = itile * 64;
  const int len = lens[b];

  __shared__ __align__(16) float QT[64][68];   // [dk][i]
  __shared__ __align__(16) float KT[64][68];   // [dk][j]
  __shared__ __align__(16) float Vs[64][68];   // [j][dk]
  __shared__ __align__(16) float Ps[64][68];   // [i][j] exp'd scores
  __shared__ __align__(16) float PT[64*128];   // [dk][c] stride 128
  __shared__ float bus[64], bvs[64];

  if (t < 64) { bus[t] = bu[h*DKH + t]; bvs[t] = bv[h*DKH + t]; }
  #pragma unroll
  for (int w = 0; w < 4; ++w) {
    const int e = t + w*256;
    const int row = e >> 4, ch = (e & 15) * 4;
    const float4 v = *(const float4*)(qkv + ((long)(b*T_ + i0 + row))*(3*DM) + h*DKH + ch);
    QT[ch+0][row] = v.x; QT[ch+1][row] = v.y; QT[ch+2][row] = v.z; QT[ch+3][row] = v.w;
  }

  float m[4], l[4], O[4][4];
  #pragma unroll
  for (int q = 0; q < 4; ++q) {
    m[q] = -1e30f; l[q] = 0.0f;
    #pragma unroll
    for (int r = 0; r < 4; ++r) O[q][r] = 0.0f;
  }
  const int c0m3 = 60 + 4*(tx - ty);   // >= 0, <= 120

  for (int jt = 0; jt <= itile; ++jt) {
    const int j0 = jt * 64;
    if (j0 >= len) break;              // remaining tiles fully masked
    const int base_prow = (T_ - 1) - i0 + j0 - 63;   // p row for c = 0
    #pragma unroll
    for (int w = 0; w < 4; ++w) {
      const int e = t + w*256;
      const int row = e >> 4, ch = (e & 15) * 4;
      const long rb = ((long)(b*T_ + j0 + row))*(3*DM) + h*DKH + ch;
      const float4 kv = *(const float4*)(qkv + rb + DM);
      const float4 vv = *(const float4*)(qkv + rb + 2*DM);
      KT[ch+0][row] = kv.x; KT[ch+1][row] = kv.y;
      KT[ch+2][row] = kv.z; KT[ch+3][row] = kv.w;
      *(float4*)&Vs[row][ch] = vv;
    }
    #pragma unroll
    for (int w = 0; w < 8; ++w) {
      const int e = t + w*256;          // 0..2047 -> 128 p-rows
      const int row = e >> 4, ch = (e & 15) * 4;
      const float4 v = *(const float4*)(p + (long)(base_prow + row)*DM + h*DKH + ch);
      PT[(ch+0)*128 + row] = v.x; PT[(ch+1)*128 + row] = v.y;
      PT[(ch+2)*128 + row] = v.z; PT[(ch+3)*128 + row] = v.w;
    }
    __syncthreads();

    float bd[4][8] = {};
    float ac[4][4] = {};
    #pragma unroll 4
    for (int kk = 0; kk < 64; ++kk) {
      const float4 q4 = *(const float4*)&QT[kk][ty*4];
      const float4 k4 = *(const float4*)&KT[kk][tx*4];
      const float4 pa = *(const float4*)&PT[kk*128 + c0m3];
      const float4 pb = *(const float4*)&PT[kk*128 + c0m3 + 4];
      const float buk = bus[kk], bvk = bvs[kk];
      const float qu[4] = {q4.x+buk, q4.y+buk, q4.z+buk, q4.w+buk};
      const float qv[4] = {q4.x+bvk, q4.y+bvk, q4.z+bvk, q4.w+bvk};
      const float kv[4] = {k4.x, k4.y, k4.z, k4.w};
      const float pv[8] = {pa.x,pa.y,pa.z,pa.w, pb.x,pb.y,pb.z,pb.w};
      #pragma unroll
      for (int q = 0; q < 4; ++q) {
        #pragma unroll
        for (int r = 0; r < 4; ++r) ac[q][r] = fmaf(qu[q], kv[r], ac[q][r]);
        #pragma unroll
        for (int s = 0; s < 8; ++s) bd[q][s] = fmaf(qv[q], pv[s], bd[q][s]);
      }
    }

    // combine + mask + online softmax
    float sv[4][4], rm[4];
    #pragma unroll
    for (int q = 0; q < 4; ++q) {
      const int gi = i0 + ty*4 + q;
      rm[q] = -1e30f;
      #pragma unroll
      for (int r = 0; r < 4; ++r) {
        const int gj = j0 + tx*4 + r;
        const float s = (gj > gi || gj >= len) ? -1e30f
                        : (ac[q][r] + bd[q][r - q + 3]) * 0.125f;
        sv[q][r] = s;
        rm[q] = fmaxf(rm[q], s);
      }
    }
    #pragma unroll
    for (int o = 1; o < 16; o <<= 1) {
      #pragma unroll
      for (int q = 0; q < 4; ++q) rm[q] = fmaxf(rm[q], __shfl_xor(rm[q], o));
    }
    float rs[4];
    #pragma unroll
    for (int q = 0; q < 4; ++q) {
      const float mn = fmaxf(m[q], rm[q]);
      const float alpha = expf(m[q] - mn);
      m[q] = mn;
      float sum = 0.0f;
      #pragma unroll
      for (int r = 0; r < 4; ++r) {
        const float e = expf(sv[q][r] - mn);
        sv[q][r] = e;
        sum += e;
      }
      rs[q] = sum;
      l[q] *= alpha;
      #pragma unroll
      for (int r = 0; r < 4; ++r) O[q][r] *= alpha;
    }
    #pragma unroll
    for (int o = 1; o < 16; o <<= 1) {
      #pragma unroll
      for (int q = 0; q < 4; ++q) rs[q] += __shfl_xor(rs[q], o);
    }
    #pragma unroll
    for (int q = 0; q < 4; ++q) l[q] += rs[q];
    #pragma unroll
    for (int q = 0; q < 4; ++q)
      *(float4*)&Ps[ty*4+q][tx*4] = make_float4(sv[q][0], sv[q][1], sv[q][2], sv[q][3]);
    __syncthreads();

    // PV: O[i][dk] += sum_j P[i][j] * V[j][dk]
    #pragma unroll 4
    for (int j = 0; j < 64; ++j) {
      const float4 v4 = *(const float4*)&Vs[j][tx*4];
      #pragma unroll
      for (int q = 0; q < 4; ++q) {
        const float a = Ps[ty*4+q][j];
        O[q][0] = fmaf(a, v4.x, O[q][0]);
        O[q][1] = fmaf(a, v4.y, O[q][1]);
        O[q][2] = fmaf(a, v4.z, O[q][2]);
        O[q][3] = fmaf(a, v4.w, O[q][3]);
      }
    }
    __syncthreads();
  }

  #pragma unroll
  for (int q = 0; q < 4; ++q) {
    const float inv = 1.0f / l[q];
    *(float4*)(att + ((long)(b*T_ + i0 + ty*4 + q))*DM + h*DKH + tx*4) =
        make_float4(O[q][0]*inv, O[q][1]*inv, O[q][2]*inv, O[q][3]*inv);
  }
}

// ---------------- x_lens tail of the tuple output ----------------
__global__ void tail_kernel(const int* __restrict__ lens, float* __restrict__ out) {
  const int i = threadIdx.x;
  if (i < B_) out[(long)ROWS*DM + i] = (float)lens[i];
}

extern "C" void kernel_launch(void* const* d_in, const int* in_sizes, int n_in,
                              void* d_out, int out_size, void* d_ws, size_t ws_size,
                              hipStream_t stream) {
  const float* x    = (const float*)d_in[0];
  const int*   lens = (const int*)  d_in[1];
  const float* embW = (const float*)d_in[2];
  const float* embB = (const float*)d_in[3];
  const float* ipW  = (const float*)d_in[4];
  const float* ipB  = (const float*)d_in[5];
  const float* posW = (const float*)d_in[6];
  const float* bu   = (const float*)d_in[7];
  const float* bv   = (const float*)d_in[8];
  const float* oW   = (const float*)d_in[9];
  const float* oB   = (const float*)d_in[10];
  const float* f1W  = (const float*)d_in[11];
  const float* f1B  = (const float*)d_in[12];
  const float* f2W  = (const float*)d_in[13];
  const float* f2B  = (const float*)d_in[14];
  float* out = (float*)d_out;

  float* ws   = (float*)d_ws;
  float* xbuf = ws;                              // ROWS*DM
  float* pe   = xbuf + (long)ROWS*DM;            // PE_ROWS*DM
  float* pall = pe   + (long)PE_ROWS*DM;         // NL*PE_ROWS*DM
  float* qkv  = pall + (long)NL*PE_ROWS*DM;      // ROWS*768
  float* att  = qkv  + (long)ROWS*3*DM;          // ROWS*DM
  float* ff   = att  + (long)ROWS*DM;            // ROWS*FFD

  embed_norm_kernel<<<ROWS, 256, 0, stream>>>(x, embW, embB, xbuf);
  pe_kernel<<<PE_ROWS, 256, 0, stream>>>(pe);
  gemm_nt<2,1,0,false,false><<<dim3((PE_ROWS+127)/128, DM/64, NL), 256, 0, stream>>>(
      pe, posW, nullptr, nullptr, pall, PE_ROWS, DM, DM,
      0L, (long)DM*DM, 0L, (long)PE_ROWS*DM);

  for (int l = 0; l < NL; ++l) {
    gemm_nt<2,2,0,true,false><<<dim3(ROWS/128, (3*DM)/128, 1), 256, 0, stream>>>(
        xbuf, ipW + (long)l*3*DM*DM, ipB + (long)l*3*DM, nullptr, qkv,
        ROWS, 3*DM, DM, 0,0,0,0);
    attn_flash<<<dim3(T_/64, NH, B_), 256, 0, stream>>>(
        qkv, pall + (long)l*PE_ROWS*DM, bu + (long)l*DM, bv + (long)l*DM, lens, att);
    gemm_nt<2,1,0,true,true><<<dim3(ROWS/128, DM/64, 1), 256, 0, stream>>>(
        att, oW + (long)l*DM*DM, oB + (long)l*DM, xbuf, xbuf, ROWS, DM, DM, 0,0,0,0);
    gemm_nt<2,2,1,true,false><<<dim3(ROWS/128, FFD/128, 1), 256, 0, stream>>>(
        xbuf, f1W + (long)l*FFD*DM, f1B + (long)l*FFD, nullptr, ff, ROWS, FFD, DM, 0,0,0,0);
    gemm_nt<2,1,0,true,true><<<dim3(ROWS/128, DM/64, 1), 256, 0, stream>>>(
        ff, f2W + (long)l*DM*FFD, f2B + (long)l*DM, xbuf, xbuf, ROWS, DM, FFD, 0,0,0,0);
    norm_kernel<<<ROWS, 256, 0, stream>>>(xbuf, (l == NL-1) ? out : xbuf);
  }
  tail_kernel<<<1, 64, 0, stream>>>(lens, out);
}

// Round 5
// 3876.299 us; speedup vs baseline: 2.7861x; 1.2370x over previous
//
#include <hip/hip_runtime.h>
#include <math.h>

#define B_ 8
#define T_ 1024
#define IN_DIM 80
#define DM 256
#define NH 4
#define DKH 64
#define FFD 2048
#define NL 6
#define PE_ROWS (2*T_-1)   /* 2047 */
#define ROWS (B_*T_)       /* 8192 */

// ---------------- embed + BasicNorm ----------------
__global__ void embed_norm_kernel(const float* __restrict__ x,
                                  const float* __restrict__ W,
                                  const float* __restrict__ b,
                                  float* __restrict__ out) {
  const int row = blockIdx.x;           // 0..ROWS-1
  const int t = threadIdx.x;            // 0..255 (= output channel)
  __shared__ float xin[IN_DIM];
  __shared__ float red[4];
  if (t < IN_DIM) xin[t] = x[(long)row*IN_DIM + t];
  __syncthreads();
  float v = b[t];
  const float* wr = W + (long)t*IN_DIM;
  #pragma unroll 8
  for (int k = 0; k < IN_DIM; ++k) v = fmaf(xin[k], wr[k], v);
  float sq = v*v;
  for (int o = 32; o > 0; o >>= 1) sq += __shfl_down(sq, o);
  if ((t & 63) == 0) red[t >> 6] = sq;
  __syncthreads();
  const float tot = red[0] + red[1] + red[2] + red[3];
  const float sc = 1.0f / sqrtf(tot * (1.0f/DM) + 0.25f);
  out[(long)row*DM + t] = v * sc;
}

// ---------------- BasicNorm (row over 256 ch) ----------------
__global__ void norm_kernel(const float* __restrict__ in, float* __restrict__ out) {
  const int row = blockIdx.x;
  const int t = threadIdx.x;            // 256
  __shared__ float red[4];
  const float v = in[(long)row*DM + t];
  float sq = v*v;
  for (int o = 32; o > 0; o >>= 1) sq += __shfl_down(sq, o);
  if ((t & 63) == 0) red[t >> 6] = sq;
  __syncthreads();
  const float tot = red[0] + red[1] + red[2] + red[3];
  out[(long)row*DM + t] = v * (1.0f / sqrtf(tot * (1.0f/DM) + 0.25f));
}

// ---------------- relative positional encoding table ----------------
__global__ void pe_kernel(float* __restrict__ pe) {
  const int r = blockIdx.x;             // 0..2046
  const int c = threadIdx.x;            // 0..255
  const int m = c >> 1;
  const float div = expf((float)(2*m) * -0.0359778921f);
  const float ang = (float)(T_ - 1 - r) * div;
  pe[(long)r*DM + c] = (c & 1) ? cosf(ang) : sinf(ang);
}

// ---------------- tiled GEMM: C = A @ W^T (+bias)(+act)(+res) ----------------
template<int MH, int NHC, int ACT, bool BIAS, bool RES>
__global__ __launch_bounds__(256) void gemm_nt(
    const float* __restrict__ A, const float* __restrict__ W,
    const float* __restrict__ bias, const float* __restrict__ res,
    float* __restrict__ C, int M, int N, int K,
    long sA, long sW, long sB, long sC) {
  constexpr int TM = 64*MH, TN = 64*NHC;
  const int z = blockIdx.z;
  A += (long)z * sA; W += (long)z * sW; C += (long)z * sC;
  if (BIAS) bias += (long)z * sB;
  if (RES)  res  += (long)z * sC;
  __shared__ __align__(16) float As[16][TM+4];   // [k][m] (A transposed in LDS)
  __shared__ __align__(16) float Bs[16][TN+4];   // [k][n]
  const int t = threadIdx.x;
  const int tx = t & 15, ty = t >> 4;
  const int m0 = blockIdx.x * TM, n0 = blockIdx.y * TN;
  float acc[4*MH][4*NHC] = {};
  for (int k0 = 0; k0 < K; k0 += 16) {
    #pragma unroll
    for (int i = 0; i < MH; ++i) {
      const int e = t + i*256;            // 0 .. TM*4-1
      const int row = e >> 2, kq = (e & 3) * 4;
      const int gm = m0 + row;
      float4 v = make_float4(0.f, 0.f, 0.f, 0.f);
      if (gm < M) v = *(const float4*)(A + (long)gm*K + k0 + kq);
      As[kq+0][row] = v.x; As[kq+1][row] = v.y;
      As[kq+2][row] = v.z; As[kq+3][row] = v.w;
    }
    #pragma unroll
    for (int i = 0; i < NHC; ++i) {
      const int e = t + i*256;
      const int row = e >> 2, kq = (e & 3) * 4;
      const float4 v = *(const float4*)(W + (long)(n0+row)*K + k0 + kq);
      Bs[kq+0][row] = v.x; Bs[kq+1][row] = v.y;
      Bs[kq+2][row] = v.z; Bs[kq+3][row] = v.w;
    }
    __syncthreads();
    #pragma unroll
    for (int kk = 0; kk < 16; ++kk) {
      float a[4*MH], bb[4*NHC];
      #pragma unroll
      for (int h = 0; h < MH; ++h) {
        const float4 v = *(const float4*)&As[kk][h*64 + ty*4];
        a[h*4+0]=v.x; a[h*4+1]=v.y; a[h*4+2]=v.z; a[h*4+3]=v.w;
      }
      #pragma unroll
      for (int h = 0; h < NHC; ++h) {
        const float4 v = *(const float4*)&Bs[kk][h*64 + tx*4];
        bb[h*4+0]=v.x; bb[h*4+1]=v.y; bb[h*4+2]=v.z; bb[h*4+3]=v.w;
      }
      #pragma unroll
      for (int q = 0; q < 4*MH; ++q)
        #pragma unroll
        for (int r = 0; r < 4*NHC; ++r)
          acc[q][r] = fmaf(a[q], bb[r], acc[q][r]);
    }
    __syncthreads();
  }
  #pragma unroll
  for (int q = 0; q < 4*MH; ++q) {
    const int gm = m0 + (q>>2)*64 + ty*4 + (q&3);
    if (gm >= M) continue;
    #pragma unroll
    for (int h = 0; h < NHC; ++h) {
      const int gn = n0 + h*64 + tx*4;
      float4 v = make_float4(acc[q][h*4+0], acc[q][h*4+1],
                             acc[q][h*4+2], acc[q][h*4+3]);
      if (BIAS) {
        const float4 b4 = *(const float4*)(bias + gn);
        v.x += b4.x; v.y += b4.y; v.z += b4.z; v.w += b4.w;
      }
      if (ACT == 1) {                       // x * sigmoid(x-1)
        v.x = v.x / (1.0f + expf(1.0f - v.x));
        v.y = v.y / (1.0f + expf(1.0f - v.y));
        v.z = v.z / (1.0f + expf(1.0f - v.z));
        v.w = v.w / (1.0f + expf(1.0f - v.w));
      }
      if (RES) {
        const float4 r4 = *(const float4*)(res + (long)gm*N + gn);
        v.x += r4.x; v.y += r4.y; v.z += r4.z; v.w += r4.w;
      }
      *(float4*)(C + (long)gm*N + gn) = v;
    }
  }
}

// ---------------- flash attention, swizzled-LDS, 80 KB -> 2 blocks/CU ----
// LDS layout: transposed tiles [kk][c] with stride 64 (QT/KT) or 128 (PT),
// physical granule = (c>>2) ^ ((kk>>2)&15)  -> 2-way-max bank conflicts on
// both the transpose staging writes and the b128 fragment reads, 16B aligned.
// Ps (exp'd scores) aliases KT (dead during PV). bu/bv via uniform s_loads.
__global__ __launch_bounds__(256) void attn_flash(
    const float* __restrict__ qkv,   // (ROWS, 768) q|k|v
    const float* __restrict__ p,     // (2T-1, 256) per-layer
    const float* __restrict__ bu, const float* __restrict__ bv,
    const int* __restrict__ lens,
    float* __restrict__ att) {       // (ROWS, 256)
  const int itile = (int)gridDim.x - 1 - (int)blockIdx.x;  // heavy tiles first
  const int h = blockIdx.y, b = blockIdx.z;
  const int t = threadIdx.x;         // 256
  const int tx = t & 15, ty = t >> 4;
  const int i0 = itile * 64;
  const int len = lens[b];

  __shared__ __align__(16) float QT[64*64];    // [dk][i] swizzled   16 KB
  __shared__ __align__(16) float KT[64*64];    // [dk][j] swz; Ps after score
  __shared__ __align__(16) float Vs[64*64];    // [j][dk] plain      16 KB
  __shared__ __align__(16) float PT[64*128];   // [dk][c] swizzled   32 KB

  const float* bu_h = bu + h*DKH;
  const float* bv_h = bv + h*DKH;

  // stage Q transposed+swizzled
  #pragma unroll
  for (int w = 0; w < 4; ++w) {
    const int e = t + w*256;
    const int row = e >> 4;                  // 0..63
    const int c4 = e & 15;                   // channel granule
    const float4 v = *(const float4*)(qkv + ((long)(b*T_ + i0 + row))*(3*DM) + h*DKH + c4*4);
    const int base = c4*256 + (((row>>2) ^ c4) << 2) + (row & 3);
    QT[base] = v.x; QT[base+64] = v.y; QT[base+128] = v.z; QT[base+192] = v.w;
  }

  float m[4], l[4], O[4][4];
  #pragma unroll
  for (int q = 0; q < 4; ++q) {
    m[q] = -1e30f; l[q] = 0.0f;
    #pragma unroll
    for (int r = 0; r < 4; ++r) O[q][r] = 0.0f;
  }
  const int c0g = 15 + tx - ty;              // P window granule, 0..30

  for (int jt = 0; jt <= itile; ++jt) {
    const int j0 = jt * 64;
    if (j0 >= len) break;                    // remaining tiles fully masked
    const int base_prow = (T_ - 1) - i0 + j0 - 63;
    // stage K (transposed+swz), V (plain row-major)
    #pragma unroll
    for (int w = 0; w < 4; ++w) {
      const int e = t + w*256;
      const int row = e >> 4;
      const int c4 = e & 15;
      const long rb = ((long)(b*T_ + j0 + row))*(3*DM) + h*DKH + c4*4;
      const float4 kv = *(const float4*)(qkv + rb + DM);
      const float4 vv = *(const float4*)(qkv + rb + 2*DM);
      const int base = c4*256 + (((row>>2) ^ c4) << 2) + (row & 3);
      KT[base] = kv.x; KT[base+64] = kv.y; KT[base+128] = kv.z; KT[base+192] = kv.w;
      *(float4*)&Vs[row*64 + c4*4] = vv;
    }
    // stage P window (128 rows) transposed+swizzled
    #pragma unroll
    for (int w = 0; w < 8; ++w) {
      const int e = t + w*256;
      const int prow = e >> 4;               // 0..127
      const int c4 = e & 15;
      const float4 v = *(const float4*)(p + (long)(base_prow + prow)*DM + h*DKH + c4*4);
      const int base = c4*512 + (((prow>>2) ^ c4) << 2) + (prow & 3);
      PT[base] = v.x; PT[base+128] = v.y; PT[base+256] = v.z; PT[base+384] = v.w;
    }
    __syncthreads();

    float ac[4][4] = {};
    float bd[4][8] = {};
    #pragma unroll 4
    for (int kk = 0; kk < 64; ++kk) {
      const int sw = (kk >> 2) & 15;
      const float4 q4 = *(const float4*)&QT[kk*64  + ((ty ^ sw) << 2)];
      const float4 k4 = *(const float4*)&KT[kk*64  + ((tx ^ sw) << 2)];
      const float4 pa = *(const float4*)&PT[kk*128 + ((c0g ^ sw) << 2)];
      const float4 pb = *(const float4*)&PT[kk*128 + (((c0g+1) ^ sw) << 2)];
      const float buk = bu_h[kk], bvk = bv_h[kk];
      const float qu[4] = {q4.x+buk, q4.y+buk, q4.z+buk, q4.w+buk};
      const float qv[4] = {q4.x+bvk, q4.y+bvk, q4.z+bvk, q4.w+bvk};
      const float kv[4] = {k4.x, k4.y, k4.z, k4.w};
      const float pv[8] = {pa.x,pa.y,pa.z,pa.w, pb.x,pb.y,pb.z,pb.w};
      #pragma unroll
      for (int q = 0; q < 4; ++q) {
        #pragma unroll
        for (int r = 0; r < 4; ++r) ac[q][r] = fmaf(qu[q], kv[r], ac[q][r]);
        #pragma unroll
        for (int s = 0; s < 8; ++s) bd[q][s] = fmaf(qv[q], pv[s], bd[q][s]);
      }
    }

    // combine + mask + online softmax
    float sv[4][4], rm[4];
    #pragma unroll
    for (int q = 0; q < 4; ++q) {
      const int gi = i0 + ty*4 + q;
      rm[q] = -1e30f;
      #pragma unroll
      for (int r = 0; r < 4; ++r) {
        const int gj = j0 + tx*4 + r;
        const float s = (gj > gi || gj >= len) ? -1e30f
                        : (ac[q][r] + bd[q][r - q + 3]) * 0.125f;
        sv[q][r] = s;
        rm[q] = fmaxf(rm[q], s);
      }
    }
    #pragma unroll
    for (int o = 1; o < 16; o <<= 1) {
      #pragma unroll
      for (int q = 0; q < 4; ++q) rm[q] = fmaxf(rm[q], __shfl_xor(rm[q], o));
    }
    float rs[4];
    #pragma unroll
    for (int q = 0; q < 4; ++q) {
      const float mn = fmaxf(m[q], rm[q]);
      const float alpha = expf(m[q] - mn);
      m[q] = mn;
      float sum = 0.0f;
      #pragma unroll
      for (int r = 0; r < 4; ++r) {
        const float e = expf(sv[q][r] - mn);
        sv[q][r] = e;
        sum += e;
      }
      rs[q] = sum;
      l[q] *= alpha;
      #pragma unroll
      for (int r = 0; r < 4; ++r) O[q][r] *= alpha;
    }
    #pragma unroll
    for (int o = 1; o < 16; o <<= 1) {
      #pragma unroll
      for (int q = 0; q < 4; ++q) rs[q] += __shfl_xor(rs[q], o);
    }
    #pragma unroll
    for (int q = 0; q < 4; ++q) l[q] += rs[q];

    __syncthreads();                        // all KT reads done
    // write Ps into KT space: [i-row as kk][j as c], swizzled
    #pragma unroll
    for (int q = 0; q < 4; ++q)
      *(float4*)&KT[(4*ty+q)*64 + ((tx ^ ty) << 2)] =
          make_float4(sv[q][0], sv[q][1], sv[q][2], sv[q][3]);
    __syncthreads();

    // PV: O[i][dk] += sum_j P[i][j] * V[j][dk]
    #pragma unroll 4
    for (int j4 = 0; j4 < 16; ++j4) {
      float4 p0 = *(const float4*)&KT[(4*ty+0)*64 + ((j4 ^ ty) << 2)];
      float4 p1 = *(const float4*)&KT[(4*ty+1)*64 + ((j4 ^ ty) << 2)];
      float4 p2 = *(const float4*)&KT[(4*ty+2)*64 + ((j4 ^ ty) << 2)];
      float4 p3 = *(const float4*)&KT[(4*ty+3)*64 + ((j4 ^ ty) << 2)];
      #pragma unroll
      for (int jj = 0; jj < 4; ++jj) {
        const float4 v4 = *(const float4*)&Vs[(j4*4+jj)*64 + tx*4];
        const float a0 = (jj==0)?p0.x:(jj==1)?p0.y:(jj==2)?p0.z:p0.w;
        const float a1 = (jj==0)?p1.x:(jj==1)?p1.y:(jj==2)?p1.z:p1.w;
        const float a2 = (jj==0)?p2.x:(jj==1)?p2.y:(jj==2)?p2.z:p2.w;
        const float a3 = (jj==0)?p3.x:(jj==1)?p3.y:(jj==2)?p3.z:p3.w;
        O[0][0] = fmaf(a0, v4.x, O[0][0]); O[0][1] = fmaf(a0, v4.y, O[0][1]);
        O[0][2] = fmaf(a0, v4.z, O[0][2]); O[0][3] = fmaf(a0, v4.w, O[0][3]);
        O[1][0] = fmaf(a1, v4.x, O[1][0]); O[1][1] = fmaf(a1, v4.y, O[1][1]);
        O[1][2] = fmaf(a1, v4.z, O[1][2]); O[1][3] = fmaf(a1, v4.w, O[1][3]);
        O[2][0] = fmaf(a2, v4.x, O[2][0]); O[2][1] = fmaf(a2, v4.y, O[2][1]);
        O[2][2] = fmaf(a2, v4.z, O[2][2]); O[2][3] = fmaf(a2, v4.w, O[2][3]);
        O[3][0] = fmaf(a3, v4.x, O[3][0]); O[3][1] = fmaf(a3, v4.y, O[3][1]);
        O[3][2] = fmaf(a3, v4.z, O[3][2]); O[3][3] = fmaf(a3, v4.w, O[3][3]);
      }
    }
    __syncthreads();                        // before next tile's staging
  }

  #pragma unroll
  for (int q = 0; q < 4; ++q) {
    const float inv = 1.0f / l[q];
    *(float4*)(att + ((long)(b*T_ + i0 + ty*4 + q))*DM + h*DKH + tx*4) =
        make_float4(O[q][0]*inv, O[q][1]*inv, O[q][2]*inv, O[q][3]*inv);
  }
}

// ---------------- x_lens tail of the tuple output ----------------
__global__ void tail_kernel(const int* __restrict__ lens, float* __restrict__ out) {
  const int i = threadIdx.x;
  if (i < B_) out[(long)ROWS*DM + i] = (float)lens[i];
}

extern "C" void kernel_launch(void* const* d_in, const int* in_sizes, int n_in,
                              void* d_out, int out_size, void* d_ws, size_t ws_size,
                              hipStream_t stream) {
  const float* x    = (const float*)d_in[0];
  const int*   lens = (const int*)  d_in[1];
  const float* embW = (const float*)d_in[2];
  const float* embB = (const float*)d_in[3];
  const float* ipW  = (const float*)d_in[4];
  const float* ipB  = (const float*)d_in[5];
  const float* posW = (const float*)d_in[6];
  const float* bu   = (const float*)d_in[7];
  const float* bv   = (const float*)d_in[8];
  const float* oW   = (const float*)d_in[9];
  const float* oB   = (const float*)d_in[10];
  const float* f1W  = (const float*)d_in[11];
  const float* f1B  = (const float*)d_in[12];
  const float* f2W  = (const float*)d_in[13];
  const float* f2B  = (const float*)d_in[14];
  float* out = (float*)d_out;

  float* ws   = (float*)d_ws;
  float* xbuf = ws;                              // ROWS*DM
  float* pe   = xbuf + (long)ROWS*DM;            // PE_ROWS*DM
  float* pall = pe   + (long)PE_ROWS*DM;         // NL*PE_ROWS*DM
  float* qkv  = pall + (long)NL*PE_ROWS*DM;      // ROWS*768
  float* att  = qkv  + (long)ROWS*3*DM;          // ROWS*DM
  float* ff   = att  + (long)ROWS*DM;            // ROWS*FFD

  embed_norm_kernel<<<ROWS, 256, 0, stream>>>(x, embW, embB, xbuf);
  pe_kernel<<<PE_ROWS, 256, 0, stream>>>(pe);
  gemm_nt<2,1,0,false,false><<<dim3((PE_ROWS+127)/128, DM/64, NL), 256, 0, stream>>>(
      pe, posW, nullptr, nullptr, pall, PE_ROWS, DM, DM,
      0L, (long)DM*DM, 0L, (long)PE_ROWS*DM);

  for (int l = 0; l < NL; ++l) {
    gemm_nt<2,2,0,true,false><<<dim3(ROWS/128, (3*DM)/128, 1), 256, 0, stream>>>(
        xbuf, ipW + (long)l*3*DM*DM, ipB + (long)l*3*DM, nullptr, qkv,
        ROWS, 3*DM, DM, 0,0,0,0);
    attn_flash<<<dim3(T_/64, NH, B_), 256, 0, stream>>>(
        qkv, pall + (long)l*PE_ROWS*DM, bu + (long)l*DM, bv + (long)l*DM, lens, att);
    gemm_nt<2,1,0,true,true><<<dim3(ROWS/128, DM/64, 1), 256, 0, stream>>>(
        att, oW + (long)l*DM*DM, oB + (long)l*DM, xbuf, xbuf, ROWS, DM, DM, 0,0,0,0);
    gemm_nt<2,2,1,true,false><<<dim3(ROWS/128, FFD/128, 1), 256, 0, stream>>>(
        xbuf, f1W + (long)l*FFD*DM, f1B + (long)l*FFD, nullptr, ff, ROWS, FFD, DM, 0,0,0,0);
    gemm_nt<2,1,0,true,true><<<dim3(ROWS/128, DM/64, 1), 256, 0, stream>>>(
        ff, f2W + (long)l*DM*FFD, f2B + (long)l*DM, xbuf, xbuf, ROWS, DM, FFD, 0,0,0,0);
    norm_kernel<<<ROWS, 256, 0, stream>>>(xbuf, (l == NL-1) ? out : xbuf);
  }
  tail_kernel<<<1, 64, 0, stream>>>(lens, out);
}

// Round 8
// 2170.826 us; speedup vs baseline: 4.9750x; 1.7856x over previous
//
#include <hip/hip_runtime.h>
#include <math.h>

#define B_ 8
#define T_ 1024
#define IN_DIM 80
#define DM 256
#define NH 4
#define DKH 64
#define FFD 2048
#define NL 6
#define PE_ROWS (2*T_-1)   /* 2047 */
#define ROWS (B_*T_)       /* 8192 */
#define FFH 1024           /* ff chunk width */

typedef __attribute__((ext_vector_type(8))) short short8v;   // 8 bf16 (4 VGPRs)
typedef __attribute__((ext_vector_type(4))) float f32x4;

#define AS1 __attribute__((address_space(1)))
#define AS3 __attribute__((address_space(3)))

// RNE fp32 -> bf16 hi/lo split. x ~= hi + lo with ~16-bit combined mantissa.
__device__ __forceinline__ void splitf(float x, ushort& h, ushort& l) {
  union { float f; unsigned u; } a, fh, b;
  a.f = x;
  unsigned uh = (a.u + 0x7fffu + ((a.u >> 16) & 1u)) & 0xffff0000u;
  h = (ushort)(uh >> 16);
  fh.u = uh;
  b.f = x - fh.f;
  l = (ushort)((b.u + 0x7fffu + ((b.u >> 16) & 1u)) >> 16);
}

// ---------------- weight fp32 -> bf16 hi/lo planes ----------------
__global__ void convert_split(const float* __restrict__ src,
                              ushort* __restrict__ hi, ushort* __restrict__ lo,
                              long n4) {   // n4 = n/4
  const long stride = (long)gridDim.x * blockDim.x;
  for (long i = (long)blockIdx.x * blockDim.x + threadIdx.x; i < n4; i += stride) {
    const float4 v = *(const float4*)(src + i*4);
    ushort h0,l0,h1,l1,h2,l2,h3,l3;
    splitf(v.x,h0,l0); splitf(v.y,h1,l1); splitf(v.z,h2,l2); splitf(v.w,h3,l3);
    *(ushort4*)(hi + i*4) = make_ushort4(h0,h1,h2,h3);
    *(ushort4*)(lo + i*4) = make_ushort4(l0,l1,l2,l3);
  }
}

// ---------------- embed + BasicNorm (+ hi/lo plane emit) ----------------
__global__ void embed_norm_kernel(const float* __restrict__ x,
                                  const float* __restrict__ W,
                                  const float* __restrict__ b,
                                  float* __restrict__ out,
                                  ushort* __restrict__ ohi, ushort* __restrict__ olo) {
  const int row = blockIdx.x;
  const int t = threadIdx.x;            // 256 (= output channel)
  __shared__ float xin[IN_DIM];
  __shared__ float red[4];
  if (t < IN_DIM) xin[t] = x[(long)row*IN_DIM + t];
  __syncthreads();
  float v = b[t];
  const float* wr = W + (long)t*IN_DIM;
  #pragma unroll 8
  for (int k = 0; k < IN_DIM; ++k) v = fmaf(xin[k], wr[k], v);
  float sq = v*v;
  for (int o = 32; o > 0; o >>= 1) sq += __shfl_down(sq, o);
  if ((t & 63) == 0) red[t >> 6] = sq;
  __syncthreads();
  const float tot = red[0] + red[1] + red[2] + red[3];
  const float val = v * (1.0f / sqrtf(tot * (1.0f/DM) + 0.25f));
  out[(long)row*DM + t] = val;
  ushort h, l; splitf(val, h, l);
  ohi[(long)row*DM + t] = h; olo[(long)row*DM + t] = l;
}

// ---------------- BasicNorm (+ hi/lo plane emit) ----------------
__global__ void norm_kernel(const float* __restrict__ in, float* __restrict__ out,
                            ushort* __restrict__ ohi, ushort* __restrict__ olo) {
  const int row = blockIdx.x;
  const int t = threadIdx.x;
  __shared__ float red[4];
  const float v = in[(long)row*DM + t];
  float sq = v*v;
  for (int o = 32; o > 0; o >>= 1) sq += __shfl_down(sq, o);
  if ((t & 63) == 0) red[t >> 6] = sq;
  __syncthreads();
  const float tot = red[0] + red[1] + red[2] + red[3];
  const float val = v * (1.0f / sqrtf(tot * (1.0f/DM) + 0.25f));
  out[(long)row*DM + t] = val;
  ushort h, l; splitf(val, h, l);
  ohi[(long)row*DM + t] = h; olo[(long)row*DM + t] = l;
}

// ---------------- relative positional encoding table ----------------
__global__ void pe_kernel(float* __restrict__ pe) {
  const int r = blockIdx.x;
  const int c = threadIdx.x;
  const int m = c >> 1;
  const float div = expf((float)(2*m) * -0.0359778921f);
  const float ang = (float)(T_ - 1 - r) * div;
  pe[(long)r*DM + c] = (c & 1) ? cosf(ang) : sinf(ang);
}

// ---------------- fp32 tiled GEMM (kept only for pe @ posW^T) ----------------
template<int MH, int NHC>
__global__ __launch_bounds__(256) void gemm_nt(
    const float* __restrict__ A, const float* __restrict__ W,
    float* __restrict__ C, int M, int N, int K,
    long sW, long sC) {
  constexpr int TM = 64*MH, TN = 64*NHC;
  const int z = blockIdx.z;
  W += (long)z * sW; C += (long)z * sC;
  __shared__ __align__(16) float As[16][TM+4];
  __shared__ __align__(16) float Bs[16][TN+4];
  const int t = threadIdx.x;
  const int tx = t & 15, ty = t >> 4;
  const int m0 = blockIdx.x * TM, n0 = blockIdx.y * TN;
  float acc[4*MH][4*NHC] = {};
  for (int k0 = 0; k0 < K; k0 += 16) {
    #pragma unroll
    for (int i = 0; i < MH; ++i) {
      const int e = t + i*256;
      const int row = e >> 2, kq = (e & 3) * 4;
      const int gm = m0 + row;
      float4 v = make_float4(0.f, 0.f, 0.f, 0.f);
      if (gm < M) v = *(const float4*)(A + (long)gm*K + k0 + kq);
      As[kq+0][row] = v.x; As[kq+1][row] = v.y;
      As[kq+2][row] = v.z; As[kq+3][row] = v.w;
    }
    #pragma unroll
    for (int i = 0; i < NHC; ++i) {
      const int e = t + i*256;
      const int row = e >> 2, kq = (e & 3) * 4;
      const float4 v = *(const float4*)(W + (long)(n0+row)*K + k0 + kq);
      Bs[kq+0][row] = v.x; Bs[kq+1][row] = v.y;
      Bs[kq+2][row] = v.z; Bs[kq+3][row] = v.w;
    }
    __syncthreads();
    #pragma unroll
    for (int kk = 0; kk < 16; ++kk) {
      float a[4*MH], bb[4*NHC];
      #pragma unroll
      for (int h = 0; h < MH; ++h) {
        const float4 v = *(const float4*)&As[kk][h*64 + ty*4];
        a[h*4+0]=v.x; a[h*4+1]=v.y; a[h*4+2]=v.z; a[h*4+3]=v.w;
      }
      #pragma unroll
      for (int h = 0; h < NHC; ++h) {
        const float4 v = *(const float4*)&Bs[kk][h*64 + tx*4];
        bb[h*4+0]=v.x; bb[h*4+1]=v.y; bb[h*4+2]=v.z; bb[h*4+3]=v.w;
      }
      #pragma unroll
      for (int q = 0; q < 4*MH; ++q)
        #pragma unroll
        for (int r = 0; r < 4*NHC; ++r)
          acc[q][r] = fmaf(a[q], bb[r], acc[q][r]);
    }
    __syncthreads();
  }
  #pragma unroll
  for (int q = 0; q < 4*MH; ++q) {
    const int gm = m0 + (q>>2)*64 + ty*4 + (q&3);
    if (gm >= M) continue;
    #pragma unroll
    for (int h = 0; h < NHC; ++h) {
      const int gn = n0 + h*64 + tx*4;
      *(float4*)(C + (long)gm*N + gn) =
        make_float4(acc[q][h*4+0], acc[q][h*4+1], acc[q][h*4+2], acc[q][h*4+3]);
    }
  }
}

// ---------------- split-bf16 MFMA GEMM: C = A @ W^T (+bias)(+act)(+res) ----
// A,W given as bf16 hi/lo planes [rows][ld]. 3-product: ah*bh+ah*bl+al*bh.
// Tile TM=128 x TN, BK=32, 4 waves (2x2). Staged via global_load_lds(16B),
// source addresses pre-swizzled (granule ^ ((row>>1)&3)) -> linear LDS dest,
// swizzled b128 reads: bijective per 1KB wave-read -> conflict-free.
template<int TN, int ACT, bool BIAS, bool RES, bool OUT32, bool EMIT>
__global__ __launch_bounds__(256) void gemm_mfma(
    const ushort* __restrict__ aH, const ushort* __restrict__ aL,
    const ushort* __restrict__ bH, const ushort* __restrict__ bL,
    const float* __restrict__ bias, const float* __restrict__ res,
    float* __restrict__ c32, ushort* __restrict__ eH, ushort* __restrict__ eL,
    int N, int K, int ldA, int ldB) {
  constexpr int TM = 128;
  constexpr int CT = TN / 32;            // col 16x16 tiles per wave
  __shared__ __align__(16) ushort ldsA[2*TM*32];
  __shared__ __align__(16) ushort ldsB[2*TN*32];
  const int t = threadIdx.x;
  const int lane = t & 63;
  const int w = t >> 6;
  const int m0 = blockIdx.x * TM, n0 = blockIdx.y * TN;
  const int wm = (w >> 1) * 64, wn = (w & 1) * (TN/2);

  f32x4 acc[4][CT];
  const f32x4 fzero = {0.0f, 0.0f, 0.0f, 0.0f};
  #pragma unroll
  for (int rt = 0; rt < 4; ++rt)
    #pragma unroll
    for (int ct = 0; ct < CT; ++ct) acc[rt][ct] = fzero;

  // wave -> plane for staging
  const ushort* sp  = (w==0) ? aH : (w==1) ? aL : (w==2) ? bH : bL;
  ushort* dst       = (w==0) ? ldsA : (w==1) ? ldsA + TM*32
                    : (w==2) ? ldsB : ldsB + TN*32;
  const int rows    = (w < 2) ? TM : TN;
  const int rbase   = (w < 2) ? m0 : n0;
  const int ld      = (w < 2) ? ldA : ldB;
  const int nInst   = rows >> 4;         // rows*4 granules / 64 lanes

  for (int k0 = 0; k0 < K; k0 += 32) {
    for (int i = 0; i < nInst; ++i) {
      const int gr  = i*64 + lane;
      const int row = gr >> 2;
      const int skg = (gr & 3) ^ ((row >> 1) & 3);
      const ushort* src = sp + (long)(rbase + row)*ld + k0 + skg*8;
      __builtin_amdgcn_global_load_lds((const AS1 void*)src,
                                       (AS3 void*)(dst + i*512), 16, 0, 0);
    }
    __syncthreads();

    short8v bh[CT], bl[CT];
    #pragma unroll
    for (int ct = 0; ct < CT; ++ct) {
      const int c  = wn + ct*16 + (lane & 15);
      const int pg = (lane >> 4) ^ ((c >> 1) & 3);
      bh[ct] = *(const short8v*)(ldsB + c*32 + pg*8);
      bl[ct] = *(const short8v*)(ldsB + TN*32 + c*32 + pg*8);
    }
    #pragma unroll
    for (int rt = 0; rt < 4; ++rt) {
      const int r  = wm + rt*16 + (lane & 15);
      const int pg = (lane >> 4) ^ ((r >> 1) & 3);
      const short8v ah = *(const short8v*)(ldsA + r*32 + pg*8);
      const short8v al = *(const short8v*)(ldsA + TM*32 + r*32 + pg*8);
      #pragma unroll
      for (int ct = 0; ct < CT; ++ct) {
        acc[rt][ct] = __builtin_amdgcn_mfma_f32_16x16x32_bf16(ah, bh[ct], acc[rt][ct], 0, 0, 0);
        acc[rt][ct] = __builtin_amdgcn_mfma_f32_16x16x32_bf16(ah, bl[ct], acc[rt][ct], 0, 0, 0);
        acc[rt][ct] = __builtin_amdgcn_mfma_f32_16x16x32_bf16(al, bh[ct], acc[rt][ct], 0, 0, 0);
      }
    }
    __syncthreads();
  }

  // epilogue: C row = (lane>>4)*4 + reg, col = lane&15  [m89-verified layout]
  #pragma unroll
  for (int rt = 0; rt < 4; ++rt) {
    #pragma unroll
    for (int ct = 0; ct < CT; ++ct) {
      const int gn = n0 + wn + ct*16 + (lane & 15);
      const float bv_ = BIAS ? bias[gn] : 0.0f;
      #pragma unroll
      for (int j = 0; j < 4; ++j) {
        const int gm = m0 + wm + rt*16 + (lane >> 4)*4 + j;
        float v = acc[rt][ct][j] + bv_;
        if (ACT == 1) v = v / (1.0f + expf(1.0f - v));   // x*sigmoid(x-1)
        if (RES) v += res[(long)gm*N + gn];
        if (OUT32) c32[(long)gm*N + gn] = v;
        if (EMIT) {
          ushort h, l; splitf(v, h, l);
          eH[(long)gm*N + gn] = h; eL[(long)gm*N + gn] = l;
        }
      }
    }
  }
}

// ---------------- flash attention, swizzled-LDS (80 KB = 2 blocks/CU) -----
// grid = 512 flat; blocks g and g+256 carry i-tiles (15-s, s): every CU-pair
// does exactly 17 j-tiles. Merged score loop: s += (q+bu)*k + (q+bu+dv)*p,
// dv = bv-bu via uniform scalar loads (bu pre-added into staged Q).
__global__ __launch_bounds__(256) void attn_flash(
    const float* __restrict__ qkv,   // (ROWS, 768) q|k|v
    const float* __restrict__ p,     // (2T-1, 256) per-layer
    const float* __restrict__ bu, const float* __restrict__ bv,
    const int* __restrict__ lens,
    ushort* __restrict__ attHi, ushort* __restrict__ attLo) {
  const int f = blockIdx.x;
  const int half = f >> 8, g = f & 255;
  const int slot = g & 7, hb = g >> 3;
  const int h = hb & 3, b = hb >> 2;
  const int itile = half ? slot : 15 - slot;
  const int t = threadIdx.x;
  const int tx = t & 15, ty = t >> 4;
  const int i0 = itile * 64;
  const int len = lens[b];

  __shared__ __align__(16) float QT[64*64];    // [dk][i] swz (holds q+bu)
  __shared__ __align__(16) float KT[64*64];    // [dk][j] swz; Ps during PV
  __shared__ __align__(16) float Vs[64*64];    // [j][dk] plain
  __shared__ __align__(16) float PT[64*128];   // [dk][c] swz

  const float* bu_h = bu + h*DKH;
  const float* bv_h = bv + h*DKH;

  // stage Q transposed+swizzled, with bu pre-added
  #pragma unroll
  for (int w = 0; w < 4; ++w) {
    const int e = t + w*256;
    const int row = e >> 4;
    const int c4 = e & 15;
    float4 v = *(const float4*)(qkv + ((long)(b*T_ + i0 + row))*(3*DM) + h*DKH + c4*4);
    const float4 bu4 = *(const float4*)(bu_h + c4*4);
    v.x += bu4.x; v.y += bu4.y; v.z += bu4.z; v.w += bu4.w;
    const int base = c4*256 + (((row>>2) ^ c4) << 2) + (row & 3);
    QT[base] = v.x; QT[base+64] = v.y; QT[base+128] = v.z; QT[base+192] = v.w;
  }

  float m[4], l[4], O[4][4];
  #pragma unroll
  for (int q = 0; q < 4; ++q) {
    m[q] = -1e30f; l[q] = 0.0f;
    #pragma unroll
    for (int r = 0; r < 4; ++r) O[q][r] = 0.0f;
  }
  const int c0g = 15 + tx - ty;              // P window granule, 0..30

  for (int jt = 0; jt <= itile; ++jt) {
    const int j0 = jt * 64;
    if (j0 >= len) break;
    const int base_prow = (T_ - 1) - i0 + j0 - 63;
    #pragma unroll
    for (int w = 0; w < 4; ++w) {
      const int e = t + w*256;
      const int row = e >> 4;
      const int c4 = e & 15;
      const long rb = ((long)(b*T_ + j0 + row))*(3*DM) + h*DKH + c4*4;
      const float4 kv = *(const float4*)(qkv + rb + DM);
      const float4 vv = *(const float4*)(qkv + rb + 2*DM);
      const int base = c4*256 + (((row>>2) ^ c4) << 2) + (row & 3);
      KT[base] = kv.x; KT[base+64] = kv.y; KT[base+128] = kv.z; KT[base+192] = kv.w;
      *(float4*)&Vs[row*64 + c4*4] = vv;
    }
    #pragma unroll
    for (int w = 0; w < 8; ++w) {
      const int e = t + w*256;
      const int prow = e >> 4;
      const int c4 = e & 15;
      const float4 v = *(const float4*)(p + (long)(base_prow + prow)*DM + h*DKH + c4*4);
      const int base = c4*512 + (((prow>>2) ^ c4) << 2) + (prow & 3);
      PT[base] = v.x; PT[base+128] = v.y; PT[base+256] = v.z; PT[base+384] = v.w;
    }
    __syncthreads();

    float sv[4][4] = {};
    #pragma unroll 4
    for (int kk = 0; kk < 64; ++kk) {
      const int sw = (kk >> 2) & 15;
      const float4 q4 = *(const float4*)&QT[kk*64  + ((ty ^ sw) << 2)];
      const float4 k4 = *(const float4*)&KT[kk*64  + ((tx ^ sw) << 2)];
      const float4 pa = *(const float4*)&PT[kk*128 + ((c0g ^ sw) << 2)];
      const float4 pb = *(const float4*)&PT[kk*128 + (((c0g+1) ^ sw) << 2)];
      const float dv = bv_h[kk] - bu_h[kk];
      const float qu[4] = {q4.x, q4.y, q4.z, q4.w};
      const float qv[4] = {q4.x+dv, q4.y+dv, q4.z+dv, q4.w+dv};
      const float kv[4] = {k4.x, k4.y, k4.z, k4.w};
      const float pv[8] = {pa.x,pa.y,pa.z,pa.w, pb.x,pb.y,pb.z,pb.w};
      #pragma unroll
      for (int q = 0; q < 4; ++q)
        #pragma unroll
        for (int r = 0; r < 4; ++r) {
          sv[q][r] = fmaf(qu[q], kv[r], sv[q][r]);
          sv[q][r] = fmaf(qv[q], pv[3 + r - q], sv[q][r]);
        }
    }

    // mask + online softmax
    float rm[4];
    #pragma unroll
    for (int q = 0; q < 4; ++q) {
      const int gi = i0 + ty*4 + q;
      rm[q] = -1e30f;
      #pragma unroll
      for (int r = 0; r < 4; ++r) {
        const int gj = j0 + tx*4 + r;
        const float s = (gj > gi || gj >= len) ? -1e30f : sv[q][r] * 0.125f;
        sv[q][r] = s;
        rm[q] = fmaxf(rm[q], s);
      }
    }
    #pragma unroll
    for (int o = 1; o < 16; o <<= 1) {
      #pragma unroll
      for (int q = 0; q < 4; ++q) rm[q] = fmaxf(rm[q], __shfl_xor(rm[q], o));
    }
    float rs[4];
    #pragma unroll
    for (int q = 0; q < 4; ++q) {
      const float mn = fmaxf(m[q], rm[q]);
      const float alpha = expf(m[q] - mn);
      m[q] = mn;
      float sum = 0.0f;
      #pragma unroll
      for (int r = 0; r < 4; ++r) {
        const float e = expf(sv[q][r] - mn);
        sv[q][r] = e;
        sum += e;
      }
      rs[q] = sum;
      l[q] *= alpha;
      #pragma unroll
      for (int r = 0; r < 4; ++r) O[q][r] *= alpha;
    }
    #pragma unroll
    for (int o = 1; o < 16; o <<= 1) {
      #pragma unroll
      for (int q = 0; q < 4; ++q) rs[q] += __shfl_xor(rs[q], o);
    }
    #pragma unroll
    for (int q = 0; q < 4; ++q) l[q] += rs[q];

    __syncthreads();                        // all KT reads done
    #pragma unroll
    for (int q = 0; q < 4; ++q)
      *(float4*)&KT[(4*ty+q)*64 + ((tx ^ ty) << 2)] =
          make_float4(sv[q][0], sv[q][1], sv[q][2], sv[q][3]);
    __syncthreads();

    #pragma unroll 4
    for (int j4 = 0; j4 < 16; ++j4) {
      float4 p0 = *(const float4*)&KT[(4*ty+0)*64 + ((j4 ^ ty) << 2)];
      float4 p1 = *(const float4*)&KT[(4*ty+1)*64 + ((j4 ^ ty) << 2)];
      float4 p2 = *(const float4*)&KT[(4*ty+2)*64 + ((j4 ^ ty) << 2)];
      float4 p3 = *(const float4*)&KT[(4*ty+3)*64 + ((j4 ^ ty) << 2)];
      #pragma unroll
      for (int jj = 0; jj < 4; ++jj) {
        const float4 v4 = *(const float4*)&Vs[(j4*4+jj)*64 + tx*4];
        const float a0 = (jj==0)?p0.x:(jj==1)?p0.y:(jj==2)?p0.z:p0.w;
        const float a1 = (jj==0)?p1.x:(jj==1)?p1.y:(jj==2)?p1.z:p1.w;
        const float a2 = (jj==0)?p2.x:(jj==1)?p2.y:(jj==2)?p2.z:p2.w;
        const float a3 = (jj==0)?p3.x:(jj==1)?p3.y:(jj==2)?p3.z:p3.w;
        O[0][0] = fmaf(a0, v4.x, O[0][0]); O[0][1] = fmaf(a0, v4.y, O[0][1]);
        O[0][2] = fmaf(a0, v4.z, O[0][2]); O[0][3] = fmaf(a0, v4.w, O[0][3]);
        O[1][0] = fmaf(a1, v4.x, O[1][0]); O[1][1] = fmaf(a1, v4.y, O[1][1]);
        O[1][2] = fmaf(a1, v4.z, O[1][2]); O[1][3] = fmaf(a1, v4.w, O[1][3]);
        O[2][0] = fmaf(a2, v4.x, O[2][0]); O[2][1] = fmaf(a2, v4.y, O[2][1]);
        O[2][2] = fmaf(a2, v4.z, O[2][2]); O[2][3] = fmaf(a2, v4.w, O[2][3]);
        O[3][0] = fmaf(a3, v4.x, O[3][0]); O[3][1] = fmaf(a3, v4.y, O[3][1]);
        O[3][2] = fmaf(a3, v4.z, O[3][2]); O[3][3] = fmaf(a3, v4.w, O[3][3]);
      }
    }
    __syncthreads();
  }

  #pragma unroll
  for (int q = 0; q < 4; ++q) {
    const float inv = 1.0f / l[q];
    const long rb = ((long)(b*T_ + i0 + ty*4 + q))*DM + h*DKH + tx*4;
    ushort h0,l0,h1,l1,h2,l2,h3,l3;
    splitf(O[q][0]*inv, h0, l0); splitf(O[q][1]*inv, h1, l1);
    splitf(O[q][2]*inv, h2, l2); splitf(O[q][3]*inv, h3, l3);
    *(ushort4*)(attHi + rb) = make_ushort4(h0,h1,h2,h3);
    *(ushort4*)(attLo + rb) = make_ushort4(l0,l1,l2,l3);
  }
}

// ---------------- x_lens tail of the tuple output ----------------
__global__ void tail_kernel(const int* __restrict__ lens, float* __restrict__ out) {
  const int i = threadIdx.x;
  if (i < B_) out[(long)ROWS*DM + i] = (float)lens[i];
}

extern "C" void kernel_launch(void* const* d_in, const int* in_sizes, int n_in,
                              void* d_out, int out_size, void* d_ws, size_t ws_size,
                              hipStream_t stream) {
  const float* x    = (const float*)d_in[0];
  const int*   lens = (const int*)  d_in[1];
  const float* embW = (const float*)d_in[2];
  const float* embB = (const float*)d_in[3];
  const float* ipW  = (const float*)d_in[4];
  const float* ipB  = (const float*)d_in[5];
  const float* posW = (const float*)d_in[6];
  const float* bu   = (const float*)d_in[7];
  const float* bv   = (const float*)d_in[8];
  const float* oW   = (const float*)d_in[9];
  const float* oB   = (const float*)d_in[10];
  const float* f1W  = (const float*)d_in[11];
  const float* f1B  = (const float*)d_in[12];
  const float* f2W  = (const float*)d_in[13];
  const float* f2B  = (const float*)d_in[14];
  float* out = (float*)d_out;

  // ---- workspace layout (peak ~102 MB) ----
  const long nIp = (long)NL*3*DM*DM, nO = (long)NL*DM*DM,
             nF1 = (long)NL*FFD*DM,  nF2 = (long)NL*DM*FFD;
  const long nAct = (long)ROWS*DM, nFFh = (long)ROWS*FFH;
  float* ws = (float*)d_ws;
  long o = 0;
  float* xbuf = ws + o;                          o += nAct;            // perm fp32 residual
  float* pall = ws + o;                          o += (long)NL*PE_ROWS*DM;
  ushort* ipH = (ushort*)(ws + o); ushort* ipL = ipH + nIp;  o += nIp;
  ushort* oH  = (ushort*)(ws + o); ushort* oL  = oH  + nO;   o += nO;
  ushort* f1H = (ushort*)(ws + o); ushort* f1L = f1H + nF1;  o += nF1;
  ushort* f2H = (ushort*)(ws + o); ushort* f2L = f2H + nF2;  o += nF2;
  // shared att/nrm planes: norm(l) writes, ip(l+1) reads; attn(l+1) overwrites
  ushort* nrmH = (ushort*)(ws + o); ushort* nrmL = nrmH + nAct;  o += nAct;
  ushort* attH = nrmH;             ushort* attL = nrmL;
  // transient union: pe (setup) / qkv (per-layer) / op+ff planes (per-layer)
  float* trans = ws + o;
  float* pe   = trans;
  float* qkv  = trans;                           // ROWS*768 fp32
  ushort* opH = (ushort*)trans;     ushort* opL = opH + nAct;
  ushort* ffH = (ushort*)(trans + nAct); ushort* ffL = ffH + nFFh;

  // weight conversion (every launch; ws is re-poisoned)
  convert_split<<<1024, 256, 0, stream>>>(ipW, ipH, ipL, nIp/4);
  convert_split<<<1024, 256, 0, stream>>>(oW,  oH,  oL,  nO/4);
  convert_split<<<2048, 256, 0, stream>>>(f1W, f1H, f1L, nF1/4);
  convert_split<<<2048, 256, 0, stream>>>(f2W, f2H, f2L, nF2/4);

  embed_norm_kernel<<<ROWS, 256, 0, stream>>>(x, embW, embB, xbuf, nrmH, nrmL);
  pe_kernel<<<PE_ROWS, 256, 0, stream>>>(pe);
  gemm_nt<2,1><<<dim3((PE_ROWS+127)/128, DM/64, NL), 256, 0, stream>>>(
      pe, posW, pall, PE_ROWS, DM, DM, (long)DM*DM, (long)PE_ROWS*DM);

  for (int l = 0; l < NL; ++l) {
    // qkv = norm(x) @ ipW^T + b       (N=768, K=256)
    gemm_mfma<128,0,true,false,true,false><<<dim3(ROWS/128, 6), 256, 0, stream>>>(
        nrmH, nrmL, ipH + (long)l*3*DM*DM, ipL + (long)l*3*DM*DM,
        ipB + (long)l*3*DM, nullptr, qkv, nullptr, nullptr, 3*DM, DM, DM, DM);
    attn_flash<<<512, 256, 0, stream>>>(
        qkv, pall + (long)l*PE_ROWS*DM, bu + (long)l*DM, bv + (long)l*DM,
        lens, attH, attL);
    // x += att @ oW^T + oB            (N=256, K=256) + emit op planes
    gemm_mfma<64,0,true,true,true,true><<<dim3(ROWS/128, 4), 256, 0, stream>>>(
        attH, attL, oH + (long)l*DM*DM, oL + (long)l*DM*DM,
        oB + (long)l*DM, xbuf, xbuf, opH, opL, DM, DM, DM, DM);
    // h = dswish(x @ f1W^T + b1), 2 chunks of N=1024; plane-only output
    for (int c = 0; c < 2; ++c) {
      gemm_mfma<128,1,true,false,false,true><<<dim3(ROWS/128, FFH/128), 256, 0, stream>>>(
          opH, opL, f1H + (long)l*FFD*DM + (long)c*FFH*DM,
          f1L + (long)l*FFD*DM + (long)c*FFH*DM,
          f1B + (long)l*FFD + c*FFH, nullptr, nullptr, ffH, ffL, FFH, DM, DM, DM);
      // x += h @ f2W^T (+ b2 on chunk 0)   (N=256, K=1024, B row stride FFD)
      if (c == 0)
        gemm_mfma<64,0,true,true,true,false><<<dim3(ROWS/128, 4), 256, 0, stream>>>(
            ffH, ffL, f2H + (long)l*DM*FFD + c*FFH, f2L + (long)l*DM*FFD + c*FFH,
            f2B + (long)l*DM, xbuf, xbuf, nullptr, nullptr, DM, FFH, FFH, FFD);
      else
        gemm_mfma<64,0,false,true,true,false><<<dim3(ROWS/128, 4), 256, 0, stream>>>(
            ffH, ffL, f2H + (long)l*DM*FFD + c*FFH, f2L + (long)l*DM*FFD + c*FFH,
            nullptr, xbuf, xbuf, nullptr, nullptr, DM, FFH, FFH, FFD);
    }
    norm_kernel<<<ROWS, 256, 0, stream>>>(xbuf, (l == NL-1) ? out : xbuf, nrmH, nrmL);
  }
  tail_kernel<<<1, 64, 0, stream>>>(lens, out);
}